// Round 1
// baseline (1357.141 us; speedup 1.0000x reference)
//
#include <hip/hip_runtime.h>

#define B_ 512
#define T_ 512
#define I_ 64
#define H_ 128
#define CHUNK 64
#define NCHUNK (T_ / CHUNK)
#define ROWS 2

__device__ __forceinline__ float fast_tanh(float x) {
    // tanh(x) = 1 - 2/(exp(2x)+1); exp->inf and ->0 both saturate correctly.
    float e = __expf(2.0f * x);
    return 1.0f - 2.0f * __builtin_amdgcn_rcpf(e + 1.0f);
}

__global__ __launch_bounds__(256, 1)
void rnn_fused_kernel(const float* __restrict__ token,
                      const float* __restrict__ W_ih,
                      const float* __restrict__ W_hh,
                      const float* __restrict__ b_ih,
                      const float* __restrict__ b_hh,
                      const float* __restrict__ W_lin,
                      const float* __restrict__ b_lin,
                      float* __restrict__ out)
{
    // LDS: double-buffered token chunk (2 x 2rows x 64steps x 64 floats = 64KB)
    //      + double-buffered hidden state (2 x 2rows x 128 floats = 2KB)
    __shared__ float tok_lds[2][ROWS][CHUNK * I_];
    __shared__ float h_lds[2][ROWS][H_];

    const int tid = threadIdx.x;
    const int r   = tid >> 7;          // batch row within block (0..1)
    const int h   = tid & (H_ - 1);    // hidden unit (0..127)
    const int b0  = blockIdx.x * ROWS;

    // ---- Weights into registers (held across all 512 steps) ----
    // w[32]  = W_hh[h][0..127]  (128 VGPRs)
    // wi[16] = W_ih[h][0..63]   (64 VGPRs)
    float4 w[32], wi[16];
    const float4* wrow = (const float4*)(W_hh + h * H_);
#pragma unroll
    for (int q = 0; q < 32; ++q) w[q] = wrow[q];
    const float4* wirow = (const float4*)(W_ih + h * I_);
#pragma unroll
    for (int q = 0; q < 16; ++q) wi[q] = wirow[q];
    const float bias = b_ih[h] + b_hh[h];

    // ---- Stage token chunk 0 (each row's chunk is 16KB contiguous) ----
    const int lr = tid >> 7;       // staging row
    const int li = tid & 127;      // 128 threads per row, 8 float4 each
    float4 st[8];
    {
        const float4* gsrc = (const float4*)(token + (size_t)(b0 + lr) * T_ * I_);
#pragma unroll
        for (int q = 0; q < 8; ++q) st[q] = gsrc[li + 128 * q];
#pragma unroll
        for (int q = 0; q < 8; ++q)
            ((float4*)&tok_lds[0][lr][0])[li + 128 * q] = st[q];
    }

    // h0 = 0
    h_lds[0][r][h] = 0.0f;
    __syncthreads();

    int cur = 0;
#pragma unroll 1
    for (int c = 0; c < NCHUNK; ++c) {
        // Prefetch next chunk into registers; stays in flight under the 64 steps.
        if (c + 1 < NCHUNK) {
            const float4* gsrc = (const float4*)(token + (size_t)(b0 + lr) * T_ * I_
                                                 + (size_t)(c + 1) * CHUNK * I_);
#pragma unroll
            for (int q = 0; q < 8; ++q) st[q] = gsrc[li + 128 * q];
        }
        const int cb = c & 1;

#pragma unroll 1
        for (int tt = 0; tt < CHUNK; ++tt) {
            const float4* tv = (const float4*)&tok_lds[cb][r][tt * I_];
            const float4* hv = (const float4*)&h_lds[cur][r][0];

            float s0 = bias, s1 = 0.f, s2 = 0.f, s3 = 0.f;
            // input projection: xp[h] = sum_i token[b,t,i] * W_ih[h,i]
#pragma unroll
            for (int q = 0; q < 16; ++q) {
                float4 t4 = tv[q];
                s0 = fmaf(t4.x, wi[q].x, s0);
                s1 = fmaf(t4.y, wi[q].y, s1);
                s2 = fmaf(t4.z, wi[q].z, s2);
                s3 = fmaf(t4.w, wi[q].w, s3);
            }
            // recurrence: + sum_j h[b,j] * W_hh[h,j]
#pragma unroll
            for (int q = 0; q < 32; ++q) {
                float4 h4 = hv[q];
                s0 = fmaf(h4.x, w[q].x, s0);
                s1 = fmaf(h4.y, w[q].y, s1);
                s2 = fmaf(h4.z, w[q].z, s2);
                s3 = fmaf(h4.w, w[q].w, s3);
            }
            float hn = fast_tanh((s0 + s1) + (s2 + s3));
            h_lds[cur ^ 1][r][h] = hn;
            __syncthreads();
            cur ^= 1;
        }

        // Commit prefetched chunk to the other token buffer.
        if (c + 1 < NCHUNK) {
#pragma unroll
            for (int q = 0; q < 8; ++q)
                ((float4*)&tok_lds[cb ^ 1][lr][0])[li + 128 * q] = st[q];
            __syncthreads();
        }
    }

    // ---- Linear head: out[b] = h_last . W_lin + b_lin ----
    const int wv = tid >> 6, lane = tid & 63;
    if (wv < ROWS) {
        float p = h_lds[cur][wv][lane] * W_lin[lane]
                + h_lds[cur][wv][lane + 64] * W_lin[lane + 64];
#pragma unroll
        for (int off = 32; off; off >>= 1) p += __shfl_down(p, off);
        if (lane == 0) out[b0 + wv] = p + b_lin[0];
    }
}

extern "C" void kernel_launch(void* const* d_in, const int* in_sizes, int n_in,
                              void* d_out, int out_size, void* d_ws, size_t ws_size,
                              hipStream_t stream) {
    const float* token = (const float*)d_in[0];
    const float* W_ih  = (const float*)d_in[1];
    const float* W_hh  = (const float*)d_in[2];
    const float* b_ih  = (const float*)d_in[3];
    const float* b_hh  = (const float*)d_in[4];
    const float* W_lin = (const float*)d_in[5];
    const float* b_lin = (const float*)d_in[6];
    float* out = (float*)d_out;

    hipLaunchKernelGGL(rnn_fused_kernel, dim3(B_ / ROWS), dim3(256), 0, stream,
                       token, W_ih, W_hh, b_ih, b_hh, W_lin, b_lin, out);
}

// Round 2
// 368.373 us; speedup vs baseline: 3.6841x; 3.6841x over previous
//
#include <hip/hip_runtime.h>

#define B_ 512
#define T_ 512
#define I_ 64
#define H_ 128
#define CHUNK 64
#define NCHUNK (T_ / CHUNK)

__device__ __forceinline__ float fast_tanh(float x) {
    // tanh(x) = 1 - 2/(exp(2x)+1); exp->inf and ->0 both saturate correctly.
    float e = __expf(2.0f * x);
    return 1.0f - 2.0f * __builtin_amdgcn_rcpf(e + 1.0f);
}

// async global->LDS, 16B per lane; LDS dest is wave-uniform base + lane*16,
// which matches linear layout when per-lane pointers are consecutive.
__device__ __forceinline__ void gload_lds16(const float* g, float* l) {
    __builtin_amdgcn_global_load_lds(
        (const __attribute__((address_space(1))) unsigned int*)g,
        (__attribute__((address_space(3))) unsigned int*)l, 16, 0, 0);
}

__global__ __launch_bounds__(256) __attribute__((amdgpu_waves_per_eu(2, 2)))
void rnn_fused_kernel(const float* __restrict__ token,
                      const float* __restrict__ W_ih,
                      const float* __restrict__ W_hh,
                      const float* __restrict__ b_ih,
                      const float* __restrict__ b_hh,
                      const float* __restrict__ W_lin,
                      const float* __restrict__ b_lin,
                      float* __restrict__ out)
{
    // One batch row per block. 256 threads: h = tid>>1 (0..127), half = tid&1.
    // Each thread owns HALF of the K dimension for its output h:
    //   W_hh[h][half*64 .. +63]  -> 16 float4 = 64 VGPR
    //   W_ih[h][half*32 .. +31]  ->  8 float4 = 32 VGPR
    __shared__ float tok_lds[2][CHUNK * I_];   // 2 x 16 KB
    __shared__ float h_lds[2][H_];             // 2 x 512 B

    const int tid  = threadIdx.x;
    const int h    = tid >> 1;
    const int half = tid & 1;
    const int b    = blockIdx.x;

    float4 w[16], wi[8];
    const float4* wrow = (const float4*)(W_hh + h * H_ + half * 64);
#pragma unroll
    for (int q = 0; q < 16; ++q) w[q] = wrow[q];
    const float4* wirow = (const float4*)(W_ih + h * I_ + half * 32);
#pragma unroll
    for (int q = 0; q < 8; ++q) wi[q] = wirow[q];
    const float bias = half ? 0.0f : (b_ih[h] + b_hh[h]);

    const float* tok_row = token + (size_t)b * T_ * I_;

    // Stage chunk 0: 4096 floats = 1024 float4; 4 per thread, linear+coalesced.
#pragma unroll
    for (int q = 0; q < 4; ++q) {
        const int f4 = q * 256 + tid;
        gload_lds16(tok_row + f4 * 4, &tok_lds[0][f4 * 4]);
    }
    if (tid < H_) h_lds[0][tid] = 0.0f;
    __syncthreads();   // drains vmcnt -> chunk 0 resident

    int cur = 0;
#pragma unroll 1
    for (int c = 0; c < NCHUNK; ++c) {
        const int cb = c & 1;
        // Prefetch next chunk into the other buffer (async; completes under
        // the first step or two of this chunk's compute).
        if (c + 1 < NCHUNK) {
            const float* gsrc = tok_row + (size_t)(c + 1) * CHUNK * I_;
#pragma unroll
            for (int q = 0; q < 4; ++q) {
                const int f4 = q * 256 + tid;
                gload_lds16(gsrc + f4 * 4, &tok_lds[cb ^ 1][f4 * 4]);
            }
        }

#pragma unroll 1
        for (int tt = 0; tt < CHUNK; ++tt) {
            const float4* tv = (const float4*)&tok_lds[cb][tt * I_ + half * 32];
            const float4* hv = (const float4*)&h_lds[cur][half * 64];

            float s0 = bias, s1 = 0.f, s2 = 0.f, s3 = 0.f;
            // half of the input projection
#pragma unroll
            for (int q = 0; q < 8; ++q) {
                float4 t4 = tv[q];
                s0 = fmaf(t4.x, wi[q].x, s0);
                s1 = fmaf(t4.y, wi[q].y, s1);
                s2 = fmaf(t4.z, wi[q].z, s2);
                s3 = fmaf(t4.w, wi[q].w, s3);
            }
            // half of the recurrence
#pragma unroll
            for (int q = 0; q < 16; ++q) {
                float4 h4 = hv[q];
                s0 = fmaf(h4.x, w[q].x, s0);
                s1 = fmaf(h4.y, w[q].y, s1);
                s2 = fmaf(h4.z, w[q].z, s2);
                s3 = fmaf(h4.w, w[q].w, s3);
            }
            float p = (s0 + s1) + (s2 + s3);
            p += __shfl_xor(p, 1);           // combine the two K-halves
            float hn = fast_tanh(p);
            if (!half) h_lds[cur ^ 1][h] = hn;
            __syncthreads();
            cur ^= 1;
        }
    }

    // Linear head: out[b] = h_last . W_lin + b_lin   (wave 0 only)
    if (tid < 64) {
        float p = h_lds[cur][tid] * W_lin[tid]
                + h_lds[cur][tid + 64] * W_lin[tid + 64];
#pragma unroll
        for (int off = 32; off; off >>= 1) p += __shfl_down(p, off);
        if (tid == 0) out[b] = p + b_lin[0];
    }
}

extern "C" void kernel_launch(void* const* d_in, const int* in_sizes, int n_in,
                              void* d_out, int out_size, void* d_ws, size_t ws_size,
                              hipStream_t stream) {
    const float* token = (const float*)d_in[0];
    const float* W_ih  = (const float*)d_in[1];
    const float* W_hh  = (const float*)d_in[2];
    const float* b_ih  = (const float*)d_in[3];
    const float* b_hh  = (const float*)d_in[4];
    const float* W_lin = (const float*)d_in[5];
    const float* b_lin = (const float*)d_in[6];
    float* out = (float*)d_out;

    hipLaunchKernelGGL(rnn_fused_kernel, dim3(B_), dim3(256), 0, stream,
                       token, W_ih, W_hh, b_ih, b_hh, W_lin, b_lin, out);
}

// Round 3
// 241.419 us; speedup vs baseline: 5.6215x; 1.5259x over previous
//
#include <hip/hip_runtime.h>

#define B_ 512
#define T_ 512
#define I_ 64
#define H_ 128
#define CHUNK 64
#define NCHUNK (T_ / CHUNK)

typedef float4 f4;

__device__ __forceinline__ float fast_tanh(float x) {
    // tanh(x) = 1 - 2/(exp(2x)+1); saturates correctly at +/-inf.
    float e = __expf(2.0f * x);
    return 1.0f - 2.0f * __builtin_amdgcn_rcpf(e + 1.0f);
}

template <int CTRL>
__device__ __forceinline__ float dppq(float x) {
    // quad_perm DPP: pure-VALU cross-lane within each 4-lane quad.
    return __int_as_float(__builtin_amdgcn_update_dpp(
        0, __float_as_int(x), CTRL, 0xF, 0xF, true));
}

__device__ __forceinline__ void gload_lds16(const float* g, float* l) {
    __builtin_amdgcn_global_load_lds(
        (const __attribute__((address_space(1))) unsigned int*)g,
        (__attribute__((address_space(3))) unsigned int*)l, 16, 0, 0);
}

#define FMA4(A, X, W)                      \
    A.x = fmaf((X).x, (W).x, A.x);         \
    A.y = fmaf((X).y, (W).y, A.y);         \
    A.z = fmaf((X).z, (W).z, A.z);         \
    A.w = fmaf((X).w, (W).w, A.w);

__global__ __launch_bounds__(256) __attribute__((amdgpu_waves_per_eu(2, 2)))
void rnn_kernel(const float* __restrict__ token,
                const float* __restrict__ W_ih,
                const float* __restrict__ W_hh,
                const float* __restrict__ b_ih,
                const float* __restrict__ b_hh,
                const float* __restrict__ W_lin,
                const float* __restrict__ b_lin,
                float* __restrict__ out)
{
    // tok_l: per step tt, 16 f4 slots; slot (m*4+q) holds tok[tt*64 + q*16 + m*4 ..+3]
    // h_l:   32 f4 slots; slot (m*4+q) holds h[q*32 + m*4 ..+3]
    // -> a wave phase (32 lanes, q=lane&3) reads 4 CONSECUTIVE f4 slots: conflict-free.
    __shared__ f4 tok_l[2][CHUNK * 16];   // 32 KB
    __shared__ f4 h_l[2][32];             // 1 KB

    const int tid = threadIdx.x;
    const int w   = tid >> 6;
    const int l   = tid & 63;
    const int q   = l & 3;                 // K-quarter
    const int Q   = (w << 4) | (l >> 2);   // quad id 0..63
    const int b   = blockIdx.x;

    // ---- weights: 2 outputs (2Q, 2Q+1) x quarter-K -> 24 f4 = 96 VGPR ----
    f4 wh0[8], wh1[8], wi0[4], wi1[4];
    {
        const f4* r0 = (const f4*)(W_hh + (2 * Q) * H_ + q * 32);
        const f4* r1 = (const f4*)(W_hh + (2 * Q + 1) * H_ + q * 32);
#pragma unroll
        for (int m = 0; m < 8; ++m) { wh0[m] = r0[m]; wh1[m] = r1[m]; }
        const f4* i0 = (const f4*)(W_ih + (2 * Q) * I_ + q * 16);
        const f4* i1 = (const f4*)(W_ih + (2 * Q + 1) * I_ + q * 16);
#pragma unroll
        for (int m = 0; m < 4; ++m) { wi0[m] = i0[m]; wi1[m] = i1[m]; }
    }
    const int   jsel    = 2 * Q + (q & 1);          // output this lane finalizes
    const float my_bias = b_ih[jsel] + b_hh[jsel];
    // permuted float offset of h[jsel] in h_l
    const int   wloc    = ((jsel >> 2) & 7) * 16 + (jsel >> 5) * 4 + (jsel & 3);
    const bool  writer  = (q < 2);

    const float* tok_row = token + (size_t)b * T_ * I_;

    // ---- stage chunk 0 (source pre-swizzled, LDS dest linear) ----
#pragma unroll
    for (int it = 0; it < 4; ++it) {
        const int S = it * 256 + tid;            // f4 slot
        const int tt = S >> 4, k = S & 15, m = k >> 2, qk = k & 3;
        gload_lds16(tok_row + tt * 64 + qk * 16 + m * 4, (float*)&tok_l[0][S]);
    }
    if (tid < H_) ((float*)h_l[0])[tid] = 0.0f;   // zeros: permutation-invariant
    asm volatile("s_waitcnt vmcnt(0) lgkmcnt(0)" ::: "memory");
    __builtin_amdgcn_s_barrier();

    f4 t4[4];
#pragma unroll
    for (int m = 0; m < 4; ++m) t4[m] = tok_l[0][m * 4 + q];   // tt=0

    // one RNN step: reads h from hrd, writes new h into hwr.
    auto STEP = [&](const f4* hrd, float* hwr, int tt, bool last_in_chunk,
                    bool has_next_chunk, int cb) {
        f4 A0 = {0.f, 0.f, 0.f, 0.f}, A1 = {0.f, 0.f, 0.f, 0.f};
        // input projection (t4 already in regs — fills h-read latency)
#pragma unroll
        for (int m = 0; m < 4; ++m) { FMA4(A0, t4[m], wi0[m]); FMA4(A1, t4[m], wi1[m]); }
        // recurrence quarter
#pragma unroll
        for (int m = 0; m < 8; ++m) {
            f4 hv = hrd[m * 4 + q];
            FMA4(A0, hv, wh0[m]);
            FMA4(A1, hv, wh1[m]);
        }
        float p0 = (A0.x + A0.y) + (A0.z + A0.w);
        float p1 = (A1.x + A1.y) + (A1.z + A1.w);
        // quad butterfly: all 4 lanes end with full sums for both outputs
        p0 += dppq<0xB1>(p0);  p1 += dppq<0xB1>(p1);   // xor 1
        p0 += dppq<0x4E>(p0);  p1 += dppq<0x4E>(p1);   // xor 2
        float hn = fast_tanh(((q & 1) ? p1 : p0) + my_bias);
        if (writer) hwr[wloc] = hn;                    // lanes q=0,1 write

        if (!last_in_chunk) {
            // prefetch next step's tok AFTER the write; counted lgkm leaves
            // them (and the chunk's global_load_lds) in flight across s_barrier.
            __builtin_amdgcn_sched_barrier(0);
#pragma unroll
            for (int m = 0; m < 4; ++m) t4[m] = tok_l[cb][(tt + 1) * 16 + m * 4 + q];
            __builtin_amdgcn_sched_barrier(0);
            asm volatile("s_waitcnt lgkmcnt(4)" ::: "memory");  // h-write done (DS in-order)
            __builtin_amdgcn_s_barrier();
        } else {
            // chunk boundary: drain the chunk prefetch once per 64 steps
            asm volatile("s_waitcnt vmcnt(0) lgkmcnt(0)" ::: "memory");
            __builtin_amdgcn_s_barrier();
            if (has_next_chunk) {
#pragma unroll
                for (int m = 0; m < 4; ++m) t4[m] = tok_l[cb ^ 1][m * 4 + q];
            }
        }
    };

#pragma unroll 1
    for (int c = 0; c < NCHUNK; ++c) {
        const int cb = c & 1;
        const bool has_next = (c + 1 < NCHUNK);
        if (has_next) {
            const float* g = tok_row + (size_t)(c + 1) * CHUNK * I_;
#pragma unroll
            for (int it = 0; it < 4; ++it) {
                const int S = it * 256 + tid;
                const int tt = S >> 4, k = S & 15, m = k >> 2, qk = k & 3;
                gload_lds16(g + tt * 64 + qk * 16 + m * 4, (float*)&tok_l[cb ^ 1][S]);
            }
        }
#pragma unroll 1
        for (int tt = 0; tt < CHUNK; tt += 2) {
            STEP((const f4*)h_l[0], (float*)h_l[1], tt, false, has_next, cb);
            STEP((const f4*)h_l[1], (float*)h_l[0], tt + 1, (tt + 1 == CHUNK - 1),
                 has_next, cb);
        }
    }

    // ---- linear head on h_l[0] (512 steps even -> final h in buffer 0) ----
    if (tid < 64) {
        const int j0 = tid, j1 = tid + 64;
        const int l0 = ((j0 >> 2) & 7) * 16 + (j0 >> 5) * 4 + (j0 & 3);
        const int l1 = ((j1 >> 2) & 7) * 16 + (j1 >> 5) * 4 + (j1 & 3);
        float p = ((const float*)h_l[0])[l0] * W_lin[j0]
                + ((const float*)h_l[0])[l1] * W_lin[j1];
#pragma unroll
        for (int off = 32; off; off >>= 1) p += __shfl_down(p, off);
        if (tid == 0) out[b] = p + b_lin[0];
    }
}

extern "C" void kernel_launch(void* const* d_in, const int* in_sizes, int n_in,
                              void* d_out, int out_size, void* d_ws, size_t ws_size,
                              hipStream_t stream) {
    const float* token = (const float*)d_in[0];
    const float* W_ih  = (const float*)d_in[1];
    const float* W_hh  = (const float*)d_in[2];
    const float* b_ih  = (const float*)d_in[3];
    const float* b_hh  = (const float*)d_in[4];
    const float* W_lin = (const float*)d_in[5];
    const float* b_lin = (const float*)d_in[6];
    float* out = (float*)d_out;

    hipLaunchKernelGGL(rnn_kernel, dim3(B_), dim3(256), 0, stream,
                       token, W_ih, W_hh, b_ih, b_hh, W_lin, b_lin, out);
}

// Round 4
// 234.335 us; speedup vs baseline: 5.7914x; 1.0302x over previous
//
#include <hip/hip_runtime.h>

#define B_ 512
#define T_ 512
#define I_ 64
#define H_ 128
#define CHUNK 64
#define NCHUNK (T_ / CHUNK)

typedef float4 f4;

__device__ __forceinline__ float fast_tanh(float x) {
    // tanh(x) = 1 - 2/(exp(2x)+1); saturates correctly at +/-inf.
    float e = __expf(2.0f * x);
    return 1.0f - 2.0f * __builtin_amdgcn_rcpf(e + 1.0f);
}

template <int CTRL, int BANK>
__device__ __forceinline__ float dppf(float x) {
    // update_dpp(old=0, src, ctrl, row_mask, bank_mask, bound_ctrl=1):
    // disabled/invalid lanes yield 0.
    return __int_as_float(__builtin_amdgcn_update_dpp(
        0, __float_as_int(x), CTRL, 0xF, BANK, true));
}

__device__ __forceinline__ void gload_lds16(const float* g, float* l) {
    __builtin_amdgcn_global_load_lds(
        (const __attribute__((address_space(1))) unsigned int*)g,
        (__attribute__((address_space(3))) unsigned int*)l, 16, 0, 0);
}

#define FMA4(A, X, W)                      \
    A.x = fmaf((X).x, (W).x, A.x);         \
    A.y = fmaf((X).y, (W).y, A.y);         \
    A.z = fmaf((X).z, (W).z, A.z);         \
    A.w = fmaf((X).w, (W).w, A.w);

// Pin a float4 into ArchVGPRs: the asm "may modify" it, so the compiler can
// neither rematerialize the load nor park it in AGPRs/scratch.
#define PIN4(v) asm volatile("" : "+v"((v).x), "+v"((v).y), "+v"((v).z), "+v"((v).w))

__global__ __launch_bounds__(512) __attribute__((amdgpu_waves_per_eu(4, 4)))
void rnn_kernel(const float* __restrict__ token,
                const float* __restrict__ W_ih,
                const float* __restrict__ W_hh,
                const float* __restrict__ b_ih,
                const float* __restrict__ b_hh,
                const float* __restrict__ W_lin,
                const float* __restrict__ b_lin,
                float* __restrict__ out)
{
    // tok_l: step tt has 16 f4 slots; slot (m2*8+e) holds tok[tt*64 + e*8 + m2*4 ..+3]
    //        -> phase m2 reads 8 CONSECUTIVE slots (128B, banks 0..31): conflict-free.
    // h_l:   32 f4 slots; slot (m*8+e) holds h[e*16 + m*4 ..+3]  (same property).
    __shared__ f4 tok_l[2][CHUNK * 16];   // 32 KB
    __shared__ f4 h_l[2][32];             // 1 KB

    const int tid = threadIdx.x;
    const int l   = tid & 63;
    const int e   = l & 7;            // K-eighth: h[e*16..+15], x[e*8..+7]
    const int G   = tid >> 3;         // output pair id 0..63 (8 consecutive lanes)
    const int b   = blockIdx.x;

    // ---- weights: 2 outputs (2G,2G+1) x eighth-K -> 12 f4 = 48 VGPR, pinned ----
    f4 wh0[4], wh1[4], wi0[2], wi1[2];
    {
        const f4* r0 = (const f4*)(W_hh + (2 * G) * H_ + e * 16);
        const f4* r1 = (const f4*)(W_hh + (2 * G + 1) * H_ + e * 16);
#pragma unroll
        for (int m = 0; m < 4; ++m) { wh0[m] = r0[m]; wh1[m] = r1[m]; }
        const f4* i0 = (const f4*)(W_ih + (2 * G) * I_ + e * 8);
        const f4* i1 = (const f4*)(W_ih + (2 * G + 1) * I_ + e * 8);
#pragma unroll
        for (int m = 0; m < 2; ++m) { wi0[m] = i0[m]; wi1[m] = i1[m]; }
#pragma unroll
        for (int m = 0; m < 4; ++m) { PIN4(wh0[m]); PIN4(wh1[m]); }
        PIN4(wi0[0]); PIN4(wi0[1]); PIN4(wi1[0]); PIN4(wi1[1]);
    }
    const int   jsel    = 2 * G + (e & 1);   // output this lane finalizes
    const float my_bias = b_ih[jsel] + b_hh[jsel];
    // float offset of h[j] in h_l: ((j>>2)&3)*32 + (j>>4)*4 + (j&3)
    const int   wloc    = ((jsel >> 2) & 3) * 32 + (jsel >> 4) * 4 + (jsel & 3);
    const bool  writer  = (e < 2);

    const float* tok_row = token + (size_t)b * T_ * I_;

    // ---- stage chunk 0 (pre-swizzled global source, linear LDS dest) ----
#pragma unroll
    for (int it = 0; it < 2; ++it) {
        const int S = it * 512 + tid;                 // f4 slot
        const int tt = S >> 4, k = S & 15, m2 = k >> 3, ek = k & 7;
        gload_lds16(tok_row + tt * 64 + ek * 8 + m2 * 4, (float*)&tok_l[0][S]);
    }
    if (tid < H_) ((float*)h_l[0])[tid] = 0.0f;       // zeros: layout-invariant
    asm volatile("s_waitcnt vmcnt(0) lgkmcnt(0)" ::: "memory");
    __builtin_amdgcn_s_barrier();

    f4 t4[2];
    t4[0] = tok_l[0][e];          // tt=0, m2=0
    t4[1] = tok_l[0][8 + e];      // tt=0, m2=1

    auto STEP = [&](const f4* hrd, float* hwr, int tt, bool last_in_chunk,
                    bool has_next_chunk, int cb) {
        f4 A0 = {0.f, 0.f, 0.f, 0.f}, A1 = {0.f, 0.f, 0.f, 0.f};
        // input projection eighth (t4 already in regs)
        FMA4(A0, t4[0], wi0[0]);  FMA4(A1, t4[0], wi1[0]);
        FMA4(A0, t4[1], wi0[1]);  FMA4(A1, t4[1], wi1[1]);
        // recurrence eighth
#pragma unroll
        for (int m = 0; m < 4; ++m) {
            f4 hv = hrd[m * 8 + e];
            FMA4(A0, hv, wh0[m]);
            FMA4(A1, hv, wh1[m]);
        }
        float p0 = (A0.x + A0.y) + (A0.z + A0.w);
        float p1 = (A1.x + A1.y) + (A1.z + A1.w);
        // 8-lane reduce, pure VALU:
        p0 += dppf<0xB1, 0xF>(p0);             // xor1
        p1 += dppf<0xB1, 0xF>(p1);
        float c = (e & 1) ? p1 : p0;           // parity select
        c += dppf<0x4E, 0xF>(c);               // xor2 (quad-internal)
        // xor4: banks 0,2 pull lane i+4 (row_shl:4); banks 1,3 pull i-4 (row_shr:4)
        float d1 = dppf<0x104, 0x5>(c);
        float d2 = dppf<0x114, 0xA>(c);
        c = c + d1 + d2;
        float hn = fast_tanh(c + my_bias);
        if (writer) hwr[wloc] = hn;            // lanes e=0,1 write 2G, 2G+1

        if (!last_in_chunk) {
            __builtin_amdgcn_sched_barrier(0);
            t4[0] = tok_l[cb][(tt + 1) * 16 + e];
            t4[1] = tok_l[cb][(tt + 1) * 16 + 8 + e];
            __builtin_amdgcn_sched_barrier(0);
            // DS completes in-order: <=2 outstanding => the h-write landed.
            asm volatile("s_waitcnt lgkmcnt(2)" ::: "memory");
            __builtin_amdgcn_s_barrier();
        } else {
            asm volatile("s_waitcnt vmcnt(0) lgkmcnt(0)" ::: "memory");
            __builtin_amdgcn_s_barrier();
            if (has_next_chunk) {
                t4[0] = tok_l[cb ^ 1][e];
                t4[1] = tok_l[cb ^ 1][8 + e];
            }
        }
    };

#pragma unroll 1
    for (int c = 0; c < NCHUNK; ++c) {
        const int cb = c & 1;
        const bool has_next = (c + 1 < NCHUNK);
        if (has_next) {
            const float* g = tok_row + (size_t)(c + 1) * CHUNK * I_;
#pragma unroll
            for (int it = 0; it < 2; ++it) {
                const int S = it * 512 + tid;
                const int tt = S >> 4, k = S & 15, m2 = k >> 3, ek = k & 7;
                gload_lds16(g + tt * 64 + ek * 8 + m2 * 4, (float*)&tok_l[cb ^ 1][S]);
            }
        }
#pragma unroll 1
        for (int tt = 0; tt < CHUNK; tt += 2) {
            STEP((const f4*)h_l[0], (float*)h_l[1], tt, false, has_next, cb);
            STEP((const f4*)h_l[1], (float*)h_l[0], tt + 1, (tt + 1 == CHUNK - 1),
                 has_next, cb);
        }
    }

    // ---- linear head on h_l[0] (512 steps even -> final h in buffer 0) ----
    if (tid < 64) {
        const int j0 = tid, j1 = tid + 64;
        const int l0 = ((j0 >> 2) & 3) * 32 + (j0 >> 4) * 4 + (j0 & 3);
        const int l1 = ((j1 >> 2) & 3) * 32 + (j1 >> 4) * 4 + (j1 & 3);
        float p = ((const float*)h_l[0])[l0] * W_lin[j0]
                + ((const float*)h_l[0])[l1] * W_lin[j1];
#pragma unroll
        for (int off = 32; off; off >>= 1) p += __shfl_down(p, off);
        if (tid == 0) out[b] = p + b_lin[0];
    }
}

extern "C" void kernel_launch(void* const* d_in, const int* in_sizes, int n_in,
                              void* d_out, int out_size, void* d_ws, size_t ws_size,
                              hipStream_t stream) {
    const float* token = (const float*)d_in[0];
    const float* W_ih  = (const float*)d_in[1];
    const float* W_hh  = (const float*)d_in[2];
    const float* b_ih  = (const float*)d_in[3];
    const float* b_hh  = (const float*)d_in[4];
    const float* W_lin = (const float*)d_in[5];
    const float* b_lin = (const float*)d_in[6];
    float* out = (float*)d_out;

    hipLaunchKernelGGL(rnn_kernel, dim3(B_), dim3(512), 0, stream,
                       token, W_ih, W_hh, b_ih, b_hh, W_lin, b_lin, out);
}